// Round 2
// baseline (110.529 us; speedup 1.0000x reference)
//
#include <hip/hip_runtime.h>

// QueryEncDec: 2 stacks x 128 layers of scalar GRU (H=in=1), T=256.
// R17 = R10 + cross-iteration inbox prefetch, pinned by VOLATILE ORDER ONLY.
//  - R10 structure verbatim: 4 waves x 64 lanes, 1 layer/lane, wavefront
//    schedule, 542-step path; DPP wave_shr:1 handoff; tagged-u64 LDS
//    mailbox; batch-8 reads validated by one ballot; collector via DPP
//    wave_shl:1; flush 4 slots per 4 steps (si==2/6); 3-phase loop;
//    hardware rcp/exp2 with folded gate constants.
//  - NEW vs R10: batch b issues the ds_read for batch b+1's slots at si==6,
//    in program order IMMEDIATELY AFTER the si==6 flush (volatile write).
//    Volatile-volatile ordering stops upward hoist past that flush, so the
//    earliest landing is consumer step 8b+6 -> producer step 8b+80 >=
//    publish(slot 8b+15) = 8b+78: margin 2 steps (~330 cy), no fence needed.
//    The read is >= 1 full cell step (~165 cy > ~130 cy LDS latency) in
//    flight before the next batch's ballot -> the lgkmcnt wait is free.
//  - R16 post-mortem: same prefetch but with sched_barrier(0) at si==7
//    REGRESSED +2.5us -- the 40x/wave full scheduling fence stopped the
//    compiler from filling si<=6 stall slots with si==7's independent work,
//    costing more than the hidden read. This version keeps scheduler
//    freedom; the only pin is the volatile fence that already exists.
//  - Why this matters at all: with #pragma unroll 1, LLVM does not
//    software-pipeline across batch iterations, so R10's batch-top read
//    latency IS exposed (~120 cy / 8 steps ~ 15 cy/step of the 193-165
//    cy/step gap). Manual cross-iteration carry (praw) is the fix.
// Post-mortems R11-R16: batch-4, flush-2, Newton rcp, read-at-top prefetch,
// and sched_barrier-pinned prefetch each regress. Inter-lane dependence
// cycle ~165 cy; DAG floor ~511x165 ~ 35 us; R10: 542 x ~193 ~ 43.7 us.
// Predicted here: ~42 us rocprof.

#define T_LEN 256
#define MBOX  320              // 0..255 data slots, 256..319 per-lane dump
typedef unsigned long long u64;
typedef unsigned int u32;

__device__ __forceinline__ float fexp2(float x) { return __builtin_amdgcn_exp2f(x); }
__device__ __forceinline__ float frcp(float x)  { return __builtin_amdgcn_rcpf(x); }

struct CellW {
    float wri, wrh, brc;   // r gate, pre-scaled by -log2(e)
    float wzi, wzh, bzc;   // z gate, pre-scaled by -log2(e)
    float wni, bni;        // n gate input half, pre-scaled by 2*log2(e)
    float wnh, bnh;        // n gate hidden half, pre-scaled by 2*log2(e)
};

__device__ __forceinline__ float cell_step(const CellW& c, float x, float h) {
    // h-leg pre-sums run while x is still in the DPP; x enters 1 fma deep.
    const float hr  = __builtin_fmaf(c.wrh, h, c.brc);
    const float hz  = __builtin_fmaf(c.wzh, h, c.bzc);
    const float ghn = __builtin_fmaf(c.wnh, h, c.bnh);
    const float gin = __builtin_fmaf(c.wni, x, c.bni);
    const float er  = fexp2(__builtin_fmaf(c.wri, x, hr));
    const float ez  = fexp2(__builtin_fmaf(c.wzi, x, hz));
    const float r   = frcp(1.0f + er);
    const float z   = frcp(1.0f + ez);
    const float en  = fexp2(__builtin_fmaf(r, ghn, gin));   // e^{2v}
    const float q   = frcp(1.0f + en);                      // n = 1-2q
    const float A   = __builtin_fmaf(z, h - 1.0f, 1.0f);
    const float B   = __builtin_fmaf(2.0f, z, -2.0f);
    return __builtin_fmaf(q, B, A);                         // (1-z)n + z h
}

template<bool MASKED, bool READ, bool PREF, bool LAST>
__device__ __forceinline__ void do_batch(
    const int s0, const int j, const int js, const CellW& c,
    volatile u64* inbox, volatile u64* outbox,
    float* __restrict__ out, float* __restrict__ dumpG,
    float& h, float& hcp, u32& coll, u64& praw)
{
    u32 bval = 0;
    if (READ) {
        // praw prefetched >= 1 full cell step ago: first check passes in
        // steady state with the lgkmcnt wait already satisfied.
        const int slot = s0 + js;
        while (__ballot((u32)(praw >> 32) == (u32)(slot + 1)) != ~0ull)
            praw = inbox[slot];         // rare fallback (timing jitter)
        bval = (u32)praw;
    }
    #pragma unroll
    for (int si = 0; si < 8; ++si) {
        const int s = s0 + si;

        // lane-0 feed (literal-index readlane); handoff via DPP old-operand
        const int fv = READ ? __builtin_amdgcn_readlane((int)bval, si) : 0;
        const int xm = __builtin_amdgcn_update_dpp(
            fv, __builtin_bit_cast(int, hcp), 0x138 /*wave_shr:1*/, 0xF, 0xF, false);
        const float x = __builtin_bit_cast(float, xm);

        const float hc = cell_step(c, x, h);
        if (MASKED) {
            const int t = s - j;
            h = ((u32)t < (u32)T_LEN) ? hc : h;
        } else {
            h = hc;                     // steady: always in-range, no cndmask
        }
        hcp = hc;

        // collector: shift history DOWN (lane m <- m+1), insert committed h
        const int cs = __builtin_amdgcn_update_dpp(
            0, (int)coll, 0x130 /*wave_shl:1*/, 0xF, 0xF, false);
        coll = (j == 63) ? __builtin_bit_cast(u32, h) : (u32)cs;

        if (si == 2 || si == 6) {       // flush every 4 steps (compile-time)
            // lane m in 60..63 holds lane-63 h for t = s + m - 126
            const int  tm   = s + j - 126;
            const bool real = (j >= 60) & (tm >= 0);
            if (!LAST) {
                const int widx = real ? tm : (T_LEN + j);    // dump: 256+j
                outbox[widx] = ((u64)(u32)(tm + 1) << 32) | (u64)coll;
            } else {                    // dec_out: coalesced 4-float store
                float* p = real ? (out + tm) : (dumpG + j);
                *p = __builtin_bit_cast(float, coll);
            }
        }

        if (PREF && si == 6) {
            // prefetch batch b+1 slots. Placed in program order AFTER the
            // si==6 volatile flush: volatile-volatile ordering is the pin.
            // Earliest landing = consumer step s0+6 = producer step s0+80
            // >= publish(s0+15) = s0+78 (margin 2 steps). No sched_barrier
            // (R16 showed the fence costs more than the hidden read).
            praw = inbox[s0 + 8 + js];
        }
    }
}

template<bool LAST>
__device__ __forceinline__ float run_wave(
    const int j, const CellW& c,
    volatile u64* inbox, volatile u64* outbox,
    float* __restrict__ out, float* __restrict__ dumpG)
{
    float h = 0.0f, hcp = 0.0f;
    u32 coll = 0;
    const int js = j & 7;

    // pre-spin: slot 11 (tag 12) is published at producer local step 74 ->
    // lag >= 74; batch s0 needs slot s0+7 by step s0+73 -> first-try passes.
    // Wave 0's inbox is the pre-tagged X mailbox: passes immediately.
    {
        u64 v = inbox[11];
        while (__ballot((u32)(v >> 32) == 12u) != ~0ull) v = inbox[11];
    }

    // batch-0 prefetch: slots 0..7 published at producer step <= 70 < 74.
    u64 praw = inbox[js];

    #pragma unroll 1
    for (int b = 0; b < 8; ++b)         // prologue: s = 0..63 (masked, reads)
        do_batch<true, true, true, LAST>(b * 8, j, js, c, inbox, outbox, out, dumpG, h, hcp, coll, praw);
    #pragma unroll 1
    for (int b = 8; b < 31; ++b)        // steady: s = 64..247 (unmasked, reads)
        do_batch<false, true, true, LAST>(b * 8, j, js, c, inbox, outbox, out, dumpG, h, hcp, coll, praw);
    // last reading batch: s = 248..255, no prefetch (epilogue reads nothing)
    do_batch<false, true, false, LAST>(31 * 8, j, js, c, inbox, outbox, out, dumpG, h, hcp, coll, praw);
    #pragma unroll 1
    for (int b = 32; b < 40; ++b)       // epilogue: s = 256..319 (masked, no reads)
        do_batch<true, false, false, LAST>(b * 8, j, js, c, inbox, outbox, out, dumpG, h, hcp, coll, praw);

    return h;
}

__global__ __launch_bounds__(256, 1) void gru_pipe17(
    const float* __restrict__ X,
    const float* __restrict__ enc_w_ih, const float* __restrict__ enc_w_hh,
    const float* __restrict__ enc_b_ih, const float* __restrict__ enc_b_hh,
    const float* __restrict__ dec_w_ih, const float* __restrict__ dec_w_hh,
    const float* __restrict__ dec_b_ih, const float* __restrict__ dec_b_hh,
    float* __restrict__ out, float* __restrict__ dumpG)
{
    const int tid = threadIdx.x;        // global layer 0..255
    const int w   = tid >> 6;           // wave 0..3
    const int j   = tid & 63;

    __shared__ u64 xsM[T_LEN];          // X as a pre-tagged mailbox
    __shared__ u64 box[4][MBOX];        // box[3] = wave-3 trash (uniform code path)

    xsM[tid] = ((u64)(u32)(tid + 1) << 32) |
               (u64)__builtin_bit_cast(u32, X[tid]);
    box[0][tid] = 0ull;                 // data slots 0..255 need tag=0
    box[1][tid] = 0ull;
    box[2][tid] = 0ull;
    box[3][tid] = 0ull;

    // per-layer params (torch gate order r,z,n), constants folded
    const int pl = tid & 127;
    const float* wip = (tid < 128) ? enc_w_ih : dec_w_ih;
    const float* whp = (tid < 128) ? enc_w_hh : dec_w_hh;
    const float* bip = (tid < 128) ? enc_b_ih : dec_b_ih;
    const float* bhp = (tid < 128) ? enc_b_hh : dec_b_hh;
    const float L2E = 1.44269504088896340736f;
    CellW c;
    c.wri = -L2E * wip[3 * pl + 0];
    c.wrh = -L2E * whp[3 * pl + 0];
    c.brc = -L2E * (bip[3 * pl + 0] + bhp[3 * pl + 0]);
    c.wzi = -L2E * wip[3 * pl + 1];
    c.wzh = -L2E * whp[3 * pl + 1];
    c.bzc = -L2E * (bip[3 * pl + 1] + bhp[3 * pl + 1]);
    c.wni = 2.0f * L2E * wip[3 * pl + 2];
    c.bni = 2.0f * L2E * bip[3 * pl + 2];
    c.wnh = 2.0f * L2E * whp[3 * pl + 2];
    c.bnh = 2.0f * L2E * bhp[3 * pl + 2];

    __syncthreads();                    // the only block barrier

    volatile u64* inbox  = (w == 0) ? xsM : box[w - 1];
    volatile u64* outbox = box[w];

    float h;
    if (w == 3) h = run_wave<true >(j, c, inbox, outbox, out, dumpG);
    else        h = run_wave<false>(j, c, inbox, outbox, out, dumpG);

    // dec_h: final hidden of decoder layers (global layers 128..255)
    if (w >= 2) out[T_LEN + 64 * (w - 2) + j] = h;
}

extern "C" void kernel_launch(void* const* d_in, const int* in_sizes, int n_in,
                              void* d_out, int out_size, void* d_ws, size_t ws_size,
                              hipStream_t stream) {
    const float* X        = (const float*)d_in[0];
    const float* enc_w_ih = (const float*)d_in[1];
    const float* enc_w_hh = (const float*)d_in[2];
    const float* enc_b_ih = (const float*)d_in[3];
    const float* enc_b_hh = (const float*)d_in[4];
    const float* dec_w_ih = (const float*)d_in[5];
    const float* dec_w_hh = (const float*)d_in[6];
    const float* dec_b_ih = (const float*)d_in[7];
    const float* dec_b_hh = (const float*)d_in[8];
    float* out = (float*)d_out;
    float* dumpG = (float*)d_ws;

    gru_pipe17<<<1, 256, 0, stream>>>(X,
                                      enc_w_ih, enc_w_hh, enc_b_ih, enc_b_hh,
                                      dec_w_ih, dec_w_hh, dec_b_ih, dec_b_hh,
                                      out, dumpG);
}

// Round 3
// 106.773 us; speedup vs baseline: 1.0352x; 1.0352x over previous
//
#include <hip/hip_runtime.h>

// QueryEncDec: 2 stacks x 128 layers of scalar GRU (H=in=1), T=256.
// FINAL (R18) = R10 verbatim -- the best-measured configuration (44.0 us
// rocprof / ~107 us harness).
//  - 4 waves x 64 lanes, 1 layer/lane; wavefront schedule, 542-step path.
//  - Intra-wave handoff: single DPP wave_shr:1, old-operand carries the
//    lane-0 feed (no cndmask on the inter-lane chain).
//  - Cross-wave handoff: tagged-u64 LDS mailbox; batch-8 reads validated by
//    one __ballot; producer collects lane-63 h via DPP wave_shl:1 and lanes
//    60..63 flush 4 tagged slots per 4 steps (si==2/6).
//  - 3-phase loop: prologue (masked)/steady (no commit cndmask)/epilogue.
//  - Hardware rcp/exp2 (gate constants folded into weights).
//
// Post-mortems R11-R17 (all regressed, +2.5..3.5 us each):
//  R11 batch-4, R12 flush-2, R13 Newton rcp, R14 read-at-top prefetch,
//  R16 sched_barrier-pinned si==7 prefetch, R17 volatile-pinned si==6
//  prefetch. R16/R17 jointly falsify the "exposed batch-top LDS read"
//  theory: volatile loads may be hoisted past non-volatile code, so the
//  compiler already lifts the batch-top ds_read above si==7's dependent
//  chain; manual prefetch only adds a loop-carried phi + peeled batch to
//  the issue stream.
//
// Ceiling statement (why this is final): the critical inter-lane cycle is
// 10 dependent instrs (DPP,fma,exp2,add,rcp,fma,exp2,add,rcp,fma) ~75-95cy
// at light-load clocks; 542 steps vs DAG floor 511 (6% structural). The
// chain is algebraically irreducible (no fused 1/(1+x), no hw sigmoid; the
// r->en dependency is serial), and every alternative decomposition
// (2 lanes/layer, k>1 layers/lane, fewer waves) computes to a strictly
// worse steps x cycle product because the h-recurrence pins one layer-step
// per wavefront step. Latency-bound: MfmaUtil 0, VALUBusy 0.14%, HBM 0.005%.

#define T_LEN 256
#define MBOX  320              // 0..255 data slots, 256..319 per-lane dump
typedef unsigned long long u64;
typedef unsigned int u32;

__device__ __forceinline__ float fexp2(float x) { return __builtin_amdgcn_exp2f(x); }
__device__ __forceinline__ float frcp(float x)  { return __builtin_amdgcn_rcpf(x); }

struct CellW {
    float wri, wrh, brc;   // r gate, pre-scaled by -log2(e)
    float wzi, wzh, bzc;   // z gate, pre-scaled by -log2(e)
    float wni, bni;        // n gate input half, pre-scaled by 2*log2(e)
    float wnh, bnh;        // n gate hidden half, pre-scaled by 2*log2(e)
};

__device__ __forceinline__ float cell_step(const CellW& c, float x, float h) {
    // h-leg pre-sums run while x is still in the DPP; x enters 1 fma deep.
    const float hr  = __builtin_fmaf(c.wrh, h, c.brc);
    const float hz  = __builtin_fmaf(c.wzh, h, c.bzc);
    const float ghn = __builtin_fmaf(c.wnh, h, c.bnh);
    const float gin = __builtin_fmaf(c.wni, x, c.bni);
    const float er  = fexp2(__builtin_fmaf(c.wri, x, hr));
    const float ez  = fexp2(__builtin_fmaf(c.wzi, x, hz));
    const float r   = frcp(1.0f + er);
    const float z   = frcp(1.0f + ez);
    const float en  = fexp2(__builtin_fmaf(r, ghn, gin));   // e^{2v}
    const float q   = frcp(1.0f + en);                      // n = 1-2q
    const float A   = __builtin_fmaf(z, h - 1.0f, 1.0f);
    const float B   = __builtin_fmaf(2.0f, z, -2.0f);
    return __builtin_fmaf(q, B, A);                         // (1-z)n + z h
}

template<bool MASKED, bool READ, bool LAST>
__device__ __forceinline__ void do_batch(
    const int s0, const int j, const int js, const CellW& c,
    volatile u64* inbox, volatile u64* outbox,
    float* __restrict__ out, float* __restrict__ dumpG,
    float& h, float& hcp, u32& coll)
{
    u32 bval = 0;
    if (READ) {                         // one ds_read_b64 + one ballot / 8 steps
        const int slot = s0 + js;
        u64 v = inbox[slot];
        while (__ballot((u32)(v >> 32) == (u32)(slot + 1)) != ~0ull)
            v = inbox[slot];            // fallback; first-try pass in steady state
        bval = (u32)v;
    }
    #pragma unroll
    for (int si = 0; si < 8; ++si) {
        const int s = s0 + si;
        // lane-0 feed (literal-index readlane); handoff via DPP old-operand
        const int fv = READ ? __builtin_amdgcn_readlane((int)bval, si) : 0;
        const int xm = __builtin_amdgcn_update_dpp(
            fv, __builtin_bit_cast(int, hcp), 0x138 /*wave_shr:1*/, 0xF, 0xF, false);
        const float x = __builtin_bit_cast(float, xm);

        const float hc = cell_step(c, x, h);
        if (MASKED) {
            const int t = s - j;
            h = ((u32)t < (u32)T_LEN) ? hc : h;
        } else {
            h = hc;                     // steady: always in-range, no cndmask
        }
        hcp = hc;

        // collector: shift history DOWN (lane m <- m+1), insert committed h
        const int cs = __builtin_amdgcn_update_dpp(
            0, (int)coll, 0x130 /*wave_shl:1*/, 0xF, 0xF, false);
        coll = (j == 63) ? __builtin_bit_cast(u32, h) : (u32)cs;

        if (si == 2 || si == 6) {       // flush every 4 steps (compile-time)
            // lane m in 60..63 holds lane-63 h for t = s + m - 126
            const int  tm   = s + j - 126;
            const bool real = (j >= 60) & (tm >= 0);
            if (!LAST) {
                const int widx = real ? tm : (T_LEN + j);    // dump: 256+j
                outbox[widx] = ((u64)(u32)(tm + 1) << 32) | (u64)coll;
            } else {                    // dec_out: coalesced 4-float store
                float* p = real ? (out + tm) : (dumpG + j);
                *p = __builtin_bit_cast(float, coll);
            }
        }
    }
}

template<bool LAST>
__device__ __forceinline__ float run_wave(
    const int j, const CellW& c,
    volatile u64* inbox, volatile u64* outbox,
    float* __restrict__ out, float* __restrict__ dumpG)
{
    float h = 0.0f, hcp = 0.0f;
    u32 coll = 0;
    const int js = j & 7;

    // pre-spin: slot 11 (tag 12) is published at producer local step 74 ->
    // lag >= 74; batch s0 needs slot s0+7 by step s0+73 -> first-try passes.
    // Wave 0's inbox is the pre-tagged X mailbox: passes immediately.
    {
        u64 v = inbox[11];
        while (__ballot((u32)(v >> 32) == 12u) != ~0ull) v = inbox[11];
    }

    #pragma unroll 1
    for (int b = 0; b < 8; ++b)         // prologue: s = 0..63 (masked, reads)
        do_batch<true, true, LAST>(b * 8, j, js, c, inbox, outbox, out, dumpG, h, hcp, coll);
    #pragma unroll 1
    for (int b = 8; b < 32; ++b)        // steady: s = 64..255 (unmasked, reads)
        do_batch<false, true, LAST>(b * 8, j, js, c, inbox, outbox, out, dumpG, h, hcp, coll);
    #pragma unroll 1
    for (int b = 32; b < 40; ++b)       // epilogue: s = 256..319 (masked, no reads)
        do_batch<true, false, LAST>(b * 8, j, js, c, inbox, outbox, out, dumpG, h, hcp, coll);

    return h;
}

__global__ __launch_bounds__(256, 1) void gru_pipe18(
    const float* __restrict__ X,
    const float* __restrict__ enc_w_ih, const float* __restrict__ enc_w_hh,
    const float* __restrict__ enc_b_ih, const float* __restrict__ enc_b_hh,
    const float* __restrict__ dec_w_ih, const float* __restrict__ dec_w_hh,
    const float* __restrict__ dec_b_ih, const float* __restrict__ dec_b_hh,
    float* __restrict__ out, float* __restrict__ dumpG)
{
    const int tid = threadIdx.x;        // global layer 0..255
    const int w   = tid >> 6;           // wave 0..3
    const int j   = tid & 63;

    __shared__ u64 xsM[T_LEN];          // X as a pre-tagged mailbox
    __shared__ u64 box[4][MBOX];        // box[3] = wave-3 trash (uniform code path)

    xsM[tid] = ((u64)(u32)(tid + 1) << 32) |
               (u64)__builtin_bit_cast(u32, X[tid]);
    box[0][tid] = 0ull;                 // data slots 0..255 need tag=0
    box[1][tid] = 0ull;
    box[2][tid] = 0ull;
    box[3][tid] = 0ull;

    // per-layer params (torch gate order r,z,n), constants folded
    const int pl = tid & 127;
    const float* wip = (tid < 128) ? enc_w_ih : dec_w_ih;
    const float* whp = (tid < 128) ? enc_w_hh : dec_w_hh;
    const float* bip = (tid < 128) ? enc_b_ih : dec_b_ih;
    const float* bhp = (tid < 128) ? enc_b_hh : dec_b_hh;
    const float L2E = 1.44269504088896340736f;
    CellW c;
    c.wri = -L2E * wip[3 * pl + 0];
    c.wrh = -L2E * whp[3 * pl + 0];
    c.brc = -L2E * (bip[3 * pl + 0] + bhp[3 * pl + 0]);
    c.wzi = -L2E * wip[3 * pl + 1];
    c.wzh = -L2E * whp[3 * pl + 1];
    c.bzc = -L2E * (bip[3 * pl + 1] + bhp[3 * pl + 1]);
    c.wni = 2.0f * L2E * wip[3 * pl + 2];
    c.bni = 2.0f * L2E * bip[3 * pl + 2];
    c.wnh = 2.0f * L2E * whp[3 * pl + 2];
    c.bnh = 2.0f * L2E * bhp[3 * pl + 2];

    __syncthreads();                    // the only block barrier

    volatile u64* inbox  = (w == 0) ? xsM : box[w - 1];
    volatile u64* outbox = box[w];

    float h;
    if (w == 3) h = run_wave<true >(j, c, inbox, outbox, out, dumpG);
    else        h = run_wave<false>(j, c, inbox, outbox, out, dumpG);

    // dec_h: final hidden of decoder layers (global layers 128..255)
    if (w >= 2) out[T_LEN + 64 * (w - 2) + j] = h;
}

extern "C" void kernel_launch(void* const* d_in, const int* in_sizes, int n_in,
                              void* d_out, int out_size, void* d_ws, size_t ws_size,
                              hipStream_t stream) {
    const float* X        = (const float*)d_in[0];
    const float* enc_w_ih = (const float*)d_in[1];
    const float* enc_w_hh = (const float*)d_in[2];
    const float* enc_b_ih = (const float*)d_in[3];
    const float* enc_b_hh = (const float*)d_in[4];
    const float* dec_w_ih = (const float*)d_in[5];
    const float* dec_w_hh = (const float*)d_in[6];
    const float* dec_b_ih = (const float*)d_in[7];
    const float* dec_b_hh = (const float*)d_in[8];
    float* out = (float*)d_out;
    float* dumpG = (float*)d_ws;

    gru_pipe18<<<1, 256, 0, stream>>>(X,
                                      enc_w_ih, enc_w_hh, enc_b_ih, enc_b_hh,
                                      dec_w_ih, dec_w_hh, dec_b_ih, dec_b_hh,
                                      out, dumpG);
}